// Round 1
// baseline (612.386 us; speedup 1.0000x reference)
//
#include <hip/hip_runtime.h>
#include <stdint.h>
#include <stddef.h>

#define IN_F 4096
#define OUT_F 4096
#define M_TOT 8192
#define BM 128
#define BN 128
#define BK 64

typedef __attribute__((ext_vector_type(8))) short short8;     // 8 x bf16 (4 VGPRs) MFMA A/B frag
typedef __attribute__((ext_vector_type(4))) float f32x4;      // MFMA C/D frag
typedef __attribute__((ext_vector_type(4))) float float4v;
typedef __attribute__((ext_vector_type(4))) unsigned short u16x4;
typedef __attribute__((ext_vector_type(8))) unsigned short u16x8;
typedef unsigned short u16;

// FP4 codebook (matches reference FP4_CODEBOOK exactly, float32 literals)
__constant__ float c_lut[16] = {
  0.0f, 0.0052f, 0.6667f, 1.0f, 0.3333f, 0.5f, 0.1667f, 0.25f,
  0.0f, -0.0052f, -0.6667f, -1.0f, -0.3333f, -0.5f, -0.1667f, -0.25f
};

// fp32 -> bf16 round-to-nearest-even
__device__ __forceinline__ u16 f2bf(float f) {
  unsigned int x = __float_as_uint(f);
  x += 0x7fffu + ((x >> 16) & 1u);
  return (u16)(x >> 16);
}

// async global->LDS, 16B per lane. LDS dest is wave-uniform base + lane*16.
__device__ __forceinline__ void gload_lds16(const u16* g, u16* lds) {
  __builtin_amdgcn_global_load_lds(
      (const __attribute__((address_space(1))) unsigned int*)g,
      (__attribute__((address_space(3))) unsigned int*)lds, 16, 0, 0);
}

// ---------------- prep kernel 1: x fp32 -> bf16 (M x K, k-major) ----------------
__global__ __launch_bounds__(256) void k_convert_x(const float* __restrict__ x,
                                                   u16* __restrict__ a) {
  const int n4 = (M_TOT * IN_F) / 4;
  const int stride = gridDim.x * blockDim.x;
  for (int t = blockIdx.x * blockDim.x + threadIdx.x; t < n4; t += stride) {
    float4v f = ((const float4v*)x)[t];
    u16x4 o;
    o.x = f2bf(f.x); o.y = f2bf(f.y); o.z = f2bf(f.z); o.w = f2bf(f.w);
    ((u16x4*)a)[t] = o;
  }
}

// ------------- prep kernel 2: packed fp4 -> bf16 W (N x K, k-major) -------------
// weight_packed[i] holds ONE byte in an int32; element 2i = high nibble, 2i+1 = low.
// scale block = element/64. Each thread: 4 int32 (int4) -> 8 bf16 (16B store).
__global__ __launch_bounds__(256) void k_dequant_w(const int* __restrict__ wp,
                                                   const float* __restrict__ scale,
                                                   u16* __restrict__ b) {
  __shared__ float lut[16];
  if (threadIdx.x < 16) lut[threadIdx.x] = c_lut[threadIdx.x];
  __syncthreads();
  const int ng = (OUT_F * IN_F / 2) / 4;  // int4 groups
  const int stride = gridDim.x * blockDim.x;
  for (int t = blockIdx.x * blockDim.x + threadIdx.x; t < ng; t += stride) {
    int4 p = ((const int4*)wp)[t];
    float s = scale[t >> 3];            // elements 8t..8t+7 share block (8t)/64 = t/8
    int by[4] = {p.x, p.y, p.z, p.w};
    u16x8 o;
#pragma unroll
    for (int q = 0; q < 4; ++q) {
      o[2 * q]     = f2bf(lut[(by[q] >> 4) & 15] * s);
      o[2 * q + 1] = f2bf(lut[by[q] & 15] * s);
    }
    ((u16x8*)b)[t] = o;
  }
}

// ---------------- main GEMM: C = A(bf16, MxK) * B(bf16, NxK)^T + bias ----------------
// m97-style: 128x128 tile, BK=64, 256 thr / 4 waves (2x2 of 64x64),
// global_load_lds width=16 staging, 16x16x32 bf16 MFMA 4x4 frags per wave.
__global__ __launch_bounds__(256) void k_gemm(const u16* __restrict__ A,
                                              const u16* __restrict__ B,
                                              const float* __restrict__ bias,
                                              float* __restrict__ C) {
  __shared__ u16 As[BM * BK];   // 16 KiB, unpadded (required by global_load_lds layout)
  __shared__ u16 Bs[BN * BK];   // 16 KiB
  const int tid  = threadIdx.x;
  const int lane = tid & 63;
  const int wave = tid >> 6;
  const int mBase = blockIdx.y * BM;
  const int nBase = blockIdx.x * BN;
  const int wm = (wave >> 1) * 64;
  const int wn = (wave & 1) * 64;

  // staging: per instr a wave covers 8 rows x 64 cols (16B = 8 bf16 per lane)
  const int srow = lane >> 3;        // row within 8-row group
  const int scol = (lane & 7) * 8;   // k offset

  // MFMA A/B operand addressing: row = lane&15, k = (lane>>4)*8 .. +8 (contiguous)
  const int frow = lane & 15;
  const int fkof = (lane >> 4) * 8;

  f32x4 acc[4][4] = {};

  for (int kt = 0; kt < IN_F; kt += BK) {
#pragma unroll
    for (int i = 0; i < 4; ++i) {
      const int r0 = wave * 32 + i * 8;   // wave-uniform LDS base row
      gload_lds16(A + (size_t)(mBase + r0 + srow) * IN_F + kt + scol, &As[r0 * BK]);
      gload_lds16(B + (size_t)(nBase + r0 + srow) * IN_F + kt + scol, &Bs[r0 * BK]);
    }
    asm volatile("s_waitcnt vmcnt(0)" ::: "memory");
    __syncthreads();

#pragma unroll
    for (int ks = 0; ks < BK; ks += 32) {
      short8 a[4], b[4];
#pragma unroll
      for (int i = 0; i < 4; ++i)
        a[i] = *(const short8*)&As[(wm + i * 16 + frow) * BK + ks + fkof];
#pragma unroll
      for (int j = 0; j < 4; ++j)
        b[j] = *(const short8*)&Bs[(wn + j * 16 + frow) * BK + ks + fkof];
#pragma unroll
      for (int i = 0; i < 4; ++i)
#pragma unroll
        for (int j = 0; j < 4; ++j)
          acc[i][j] = __builtin_amdgcn_mfma_f32_16x16x32_bf16(a[i], b[j], acc[i][j], 0, 0, 0);
    }
    __syncthreads();
  }

  // epilogue: C/D layout col = lane&15, row = (lane>>4)*4 + reg   [m89-verified]
  const int ccol = lane & 15;
  const int crow = (lane >> 4) * 4;
#pragma unroll
  for (int j = 0; j < 4; ++j) {
    const int col = nBase + wn + j * 16 + ccol;
    const float bv = bias[col];
#pragma unroll
    for (int i = 0; i < 4; ++i) {
      const size_t rb = (size_t)(mBase + wm + i * 16 + crow) * OUT_F + col;
#pragma unroll
      for (int t = 0; t < 4; ++t)
        C[rb + (size_t)t * OUT_F] = acc[i][j][t] + bv;
    }
  }
}

// -------- fallback: fully fused (no workspace), register-staged conversion --------
__global__ __launch_bounds__(256) void k_gemm_fused(const float* __restrict__ X,
                                                    const int* __restrict__ WP,
                                                    const float* __restrict__ scale,
                                                    const float* __restrict__ bias,
                                                    float* __restrict__ C) {
  __shared__ u16 As[BM * BK];
  __shared__ u16 Bs[BN * BK];
  __shared__ float lut[16];
  const int tid = threadIdx.x;
  if (tid < 16) lut[tid] = c_lut[tid];
  const int lane = tid & 63;
  const int wave = tid >> 6;
  const int mBase = blockIdx.y * BM;
  const int nBase = blockIdx.x * BN;
  const int wm = (wave >> 1) * 64;
  const int wn = (wave & 1) * 64;
  const int frow = lane & 15;
  const int fkof = (lane >> 4) * 8;
  f32x4 acc[4][4] = {};
  __syncthreads();  // lut ready

  for (int kt = 0; kt < IN_F; kt += BK) {
    // stage A: 128x64 fp32 -> bf16; 2048 float4 groups, 8 per thread
#pragma unroll
    for (int i = 0; i < 8; ++i) {
      const int g = tid + i * 256;
      const int r = g >> 4, c = (g & 15) * 4;
      float4v f = *(const float4v*)&X[(size_t)(mBase + r) * IN_F + kt + c];
      u16x4 o;
      o.x = f2bf(f.x); o.y = f2bf(f.y); o.z = f2bf(f.z); o.w = f2bf(f.w);
      *(u16x4*)&As[r * BK + c] = o;
    }
    // stage B: 128 rows x 8 int4 groups (each int4 = 4 bytes = 8 weights)
#pragma unroll
    for (int i = 0; i < 4; ++i) {
      const int g = tid + i * 256;
      const int r = g >> 3, c4 = (g & 7) * 4;
      int4 p = *(const int4*)&WP[(size_t)(nBase + r) * (IN_F / 2) + (kt >> 1) + c4];
      const float s = scale[(nBase + r) * 64 + (kt >> 6)];
      int by[4] = {p.x, p.y, p.z, p.w};
      u16x8 o;
#pragma unroll
      for (int q = 0; q < 4; ++q) {
        o[2 * q]     = f2bf(lut[(by[q] >> 4) & 15] * s);
        o[2 * q + 1] = f2bf(lut[by[q] & 15] * s);
      }
      *(u16x8*)&Bs[r * BK + c4 * 2] = o;
    }
    __syncthreads();
#pragma unroll
    for (int ks = 0; ks < BK; ks += 32) {
      short8 a[4], b[4];
#pragma unroll
      for (int i = 0; i < 4; ++i)
        a[i] = *(const short8*)&As[(wm + i * 16 + frow) * BK + ks + fkof];
#pragma unroll
      for (int j = 0; j < 4; ++j)
        b[j] = *(const short8*)&Bs[(wn + j * 16 + frow) * BK + ks + fkof];
#pragma unroll
      for (int i = 0; i < 4; ++i)
#pragma unroll
        for (int j = 0; j < 4; ++j)
          acc[i][j] = __builtin_amdgcn_mfma_f32_16x16x32_bf16(a[i], b[j], acc[i][j], 0, 0, 0);
    }
    __syncthreads();
  }

  const int ccol = lane & 15;
  const int crow = (lane >> 4) * 4;
#pragma unroll
  for (int j = 0; j < 4; ++j) {
    const int col = nBase + wn + j * 16 + ccol;
    const float bv = bias[col];
#pragma unroll
    for (int i = 0; i < 4; ++i) {
      const size_t rb = (size_t)(mBase + wm + i * 16 + crow) * OUT_F + col;
#pragma unroll
      for (int t = 0; t < 4; ++t)
        C[rb + (size_t)t * OUT_F] = acc[i][j][t] + bv;
    }
  }
}

extern "C" void kernel_launch(void* const* d_in, const int* in_sizes, int n_in,
                              void* d_out, int out_size, void* d_ws, size_t ws_size,
                              hipStream_t stream) {
  const float* x  = (const float*)d_in[0];
  const int*   wp = (const int*)d_in[1];
  const float* sc = (const float*)d_in[2];
  const float* bi = (const float*)d_in[3];
  float* out = (float*)d_out;

  const size_t bBytes = (size_t)OUT_F * IN_F * 2;   // 33.5 MB bf16 W
  const size_t aBytes = (size_t)M_TOT * IN_F * 2;   // 67 MB bf16 x
  dim3 grid(OUT_F / BN, M_TOT / BM);                // (32, 64)

  if (ws_size >= aBytes + bBytes) {
    u16* B = (u16*)d_ws;
    u16* A = (u16*)((char*)d_ws + bBytes);
    k_dequant_w<<<2048, 256, 0, stream>>>(wp, sc, B);
    k_convert_x<<<4096, 256, 0, stream>>>(x, A);
    k_gemm<<<grid, 256, 0, stream>>>(A, B, bi, out);
  } else {
    k_gemm_fused<<<grid, 256, 0, stream>>>(x, wp, sc, bi, out);
  }
}

// Round 2
// 549.533 us; speedup vs baseline: 1.1144x; 1.1144x over previous
//
#include <hip/hip_runtime.h>
#include <stdint.h>
#include <stddef.h>

#define IN_F 4096
#define OUT_F 4096
#define M_TOT 8192
#define BM 128
#define BN 128
#define BK 64

typedef __attribute__((ext_vector_type(8))) short short8;     // 8 x bf16 (4 VGPRs) MFMA A/B frag
typedef __attribute__((ext_vector_type(4))) float f32x4;      // MFMA C/D frag
typedef __attribute__((ext_vector_type(4))) float float4v;
typedef __attribute__((ext_vector_type(4))) unsigned short u16x4;
typedef __attribute__((ext_vector_type(8))) unsigned short u16x8;
typedef unsigned short u16;

// FP4 codebook (matches reference FP4_CODEBOOK exactly)
__constant__ float c_lut[16] = {
  0.0f, 0.0052f, 0.6667f, 1.0f, 0.3333f, 0.5f, 0.1667f, 0.25f,
  0.0f, -0.0052f, -0.6667f, -1.0f, -0.3333f, -0.5f, -0.1667f, -0.25f
};

// fp32 -> bf16 round-to-nearest-even
__device__ __forceinline__ u16 f2bf(float f) {
  unsigned int x = __float_as_uint(f);
  x += 0x7fffu + ((x >> 16) & 1u);
  return (u16)(x >> 16);
}

// async global->LDS, 16B per lane. LDS dest is wave-uniform base + lane*16.
__device__ __forceinline__ void gload_lds16(const u16* g, u16* lds) {
  __builtin_amdgcn_global_load_lds(
      (const __attribute__((address_space(1))) unsigned int*)g,
      (__attribute__((address_space(3))) unsigned int*)lds, 16, 0, 0);
}

// ---------------- prep kernel 1: x fp32 -> bf16 (M x K, k-major) ----------------
__global__ __launch_bounds__(256) void k_convert_x(const float* __restrict__ x,
                                                   u16* __restrict__ a) {
  const int n8 = (M_TOT * IN_F) / 8;   // u16x8 groups
  const int stride = gridDim.x * blockDim.x;
  for (int t = blockIdx.x * blockDim.x + threadIdx.x; t < n8; t += stride) {
    float4v f0 = ((const float4v*)x)[2 * t];
    float4v f1 = ((const float4v*)x)[2 * t + 1];
    u16x8 o;
    o[0] = f2bf(f0.x); o[1] = f2bf(f0.y); o[2] = f2bf(f0.z); o[3] = f2bf(f0.w);
    o[4] = f2bf(f1.x); o[5] = f2bf(f1.y); o[6] = f2bf(f1.z); o[7] = f2bf(f1.w);
    ((u16x8*)a)[t] = o;
  }
}

// ------------- prep kernel 2: packed fp4 -> bf16 W (N x K, k-major) -------------
__global__ __launch_bounds__(256) void k_dequant_w(const int* __restrict__ wp,
                                                   const float* __restrict__ scale,
                                                   u16* __restrict__ b) {
  __shared__ float lut[16];
  if (threadIdx.x < 16) lut[threadIdx.x] = c_lut[threadIdx.x];
  __syncthreads();
  const int ng = (OUT_F * IN_F / 2) / 4;  // int4 groups
  const int stride = gridDim.x * blockDim.x;
  for (int t = blockIdx.x * blockDim.x + threadIdx.x; t < ng; t += stride) {
    int4 p = ((const int4*)wp)[t];
    float s = scale[t >> 3];            // elements 8t..8t+7 share block t/8
    int by[4] = {p.x, p.y, p.z, p.w};
    u16x8 o;
#pragma unroll
    for (int q = 0; q < 4; ++q) {
      o[2 * q]     = f2bf(lut[(by[q] >> 4) & 15] * s);
      o[2 * q + 1] = f2bf(lut[by[q] & 15] * s);
    }
    ((u16x8*)b)[t] = o;
  }
}

// ---------------- main GEMM: C = A(bf16, MxK) * B(bf16, NxK)^T + bias ----------------
// 128x128 tile, BK=64, 256 thr / 4 waves (2x2 of 64x64), global_load_lds width=16,
// 16x16x32 bf16 MFMA 4x4 frags per wave.
// LDS XOR-swizzle: LDS chunk p (16B) of row r holds GLOBAL chunk p ^ (r&7).
// Staging picks global chunk (lane&7)^srow; fragment reads chunk gc^(r&7).
// This spreads the 16-lane frow group across all 8 bank-groups (2-way = free).
__global__ __launch_bounds__(256) void k_gemm(const u16* __restrict__ A,
                                              const u16* __restrict__ B,
                                              const float* __restrict__ bias,
                                              float* __restrict__ C) {
  __shared__ u16 As[BM * BK];   // 16 KiB
  __shared__ u16 Bs[BN * BK];   // 16 KiB
  const int tid  = threadIdx.x;
  const int lane = tid & 63;
  const int wave = tid >> 6;
  const int mBase = blockIdx.y * BM;
  const int nBase = blockIdx.x * BN;
  const int wm = (wave >> 1) * 64;
  const int wn = (wave & 1) * 64;

  // staging: wave covers 8 rows x 64 cols per instr; XOR-swizzled global chunk
  const int srow = lane >> 3;                          // 0..7
  const int scol = ((lane & 7) ^ srow) * 8;            // swizzled k offset (elements)

  // MFMA A/B operand addressing
  const int frow = lane & 15;
  const int fx   = lane & 7;        // = frow & 7, swizzle key
  const int cq   = lane >> 4;       // quad id: k chunk offset within step

  f32x4 acc[4][4] = {};

  for (int kt = 0; kt < IN_F; kt += BK) {
#pragma unroll
    for (int i = 0; i < 4; ++i) {
      const int r0 = wave * 32 + i * 8;   // wave-uniform LDS base row (multiple of 8)
      gload_lds16(A + (size_t)(mBase + r0 + srow) * IN_F + kt + scol, &As[r0 * BK]);
      gload_lds16(B + (size_t)(nBase + r0 + srow) * IN_F + kt + scol, &Bs[r0 * BK]);
    }
    asm volatile("s_waitcnt vmcnt(0)" ::: "memory");
    __syncthreads();

#pragma unroll
    for (int ks = 0; ks < BK; ks += 32) {
      const int co = (((ks >> 3) + cq) ^ fx) << 3;   // swizzled element offset in row
      short8 a[4], b[4];
#pragma unroll
      for (int i = 0; i < 4; ++i)
        a[i] = *(const short8*)&As[(wm + i * 16 + frow) * BK + co];
#pragma unroll
      for (int j = 0; j < 4; ++j)
        b[j] = *(const short8*)&Bs[(wn + j * 16 + frow) * BK + co];
#pragma unroll
      for (int i = 0; i < 4; ++i)
#pragma unroll
        for (int j = 0; j < 4; ++j)
          acc[i][j] = __builtin_amdgcn_mfma_f32_16x16x32_bf16(a[i], b[j], acc[i][j], 0, 0, 0);
    }
    __syncthreads();
  }

  // epilogue: C/D layout col = lane&15, row = (lane>>4)*4 + reg   [m89-verified]
  const int ccol = lane & 15;
  const int crow = (lane >> 4) * 4;
#pragma unroll
  for (int j = 0; j < 4; ++j) {
    const int col = nBase + wn + j * 16 + ccol;
    const float bv = bias[col];
#pragma unroll
    for (int i = 0; i < 4; ++i) {
      const size_t rb = (size_t)(mBase + wm + i * 16 + crow) * OUT_F + col;
#pragma unroll
      for (int t = 0; t < 4; ++t)
        C[rb + (size_t)t * OUT_F] = acc[i][j][t] + bv;
    }
  }
}

// -------- fallback: fully fused (no workspace), register-staged conversion --------
__global__ __launch_bounds__(256) void k_gemm_fused(const float* __restrict__ X,
                                                    const int* __restrict__ WP,
                                                    const float* __restrict__ scale,
                                                    const float* __restrict__ bias,
                                                    float* __restrict__ C) {
  __shared__ u16 As[BM * BK];
  __shared__ u16 Bs[BN * BK];
  __shared__ float lut[16];
  const int tid = threadIdx.x;
  if (tid < 16) lut[tid] = c_lut[tid];
  const int lane = tid & 63;
  const int wave = tid >> 6;
  const int mBase = blockIdx.y * BM;
  const int nBase = blockIdx.x * BN;
  const int wm = (wave >> 1) * 64;
  const int wn = (wave & 1) * 64;
  const int frow = lane & 15;
  const int fx   = lane & 7;
  const int cq   = lane >> 4;
  f32x4 acc[4][4] = {};
  __syncthreads();  // lut ready

  for (int kt = 0; kt < IN_F; kt += BK) {
    // stage A: 128x64 fp32 -> bf16, swizzled store
#pragma unroll
    for (int i = 0; i < 8; ++i) {
      const int g = tid + i * 256;
      const int r = g >> 4, c = (g & 15) * 4;
      float4v f = *(const float4v*)&X[(size_t)(mBase + r) * IN_F + kt + c];
      u16x4 o;
      o.x = f2bf(f.x); o.y = f2bf(f.y); o.z = f2bf(f.z); o.w = f2bf(f.w);
      *(u16x4*)&As[r * BK + ((((c >> 3) ^ (r & 7)) << 3) | (c & 7))] = o;
    }
    // stage B: swizzled store
#pragma unroll
    for (int i = 0; i < 4; ++i) {
      const int g = tid + i * 256;
      const int r = g >> 3, c4 = (g & 7) * 4;
      int4 p = *(const int4*)&WP[(size_t)(nBase + r) * (IN_F / 2) + (kt >> 1) + c4];
      const float s = scale[(nBase + r) * 64 + (kt >> 6)];
      int by[4] = {p.x, p.y, p.z, p.w};
      u16x8 o;
#pragma unroll
      for (int q = 0; q < 4; ++q) {
        o[2 * q]     = f2bf(lut[(by[q] >> 4) & 15] * s);
        o[2 * q + 1] = f2bf(lut[by[q] & 15] * s);
      }
      *(u16x8*)&Bs[r * BK + (((g & 7) ^ (r & 7)) << 3)] = o;
    }
    __syncthreads();
#pragma unroll
    for (int ks = 0; ks < BK; ks += 32) {
      const int co = (((ks >> 3) + cq) ^ fx) << 3;
      short8 a[4], b[4];
#pragma unroll
      for (int i = 0; i < 4; ++i)
        a[i] = *(const short8*)&As[(wm + i * 16 + frow) * BK + co];
#pragma unroll
      for (int j = 0; j < 4; ++j)
        b[j] = *(const short8*)&Bs[(wn + j * 16 + frow) * BK + co];
#pragma unroll
      for (int i = 0; i < 4; ++i)
#pragma unroll
        for (int j = 0; j < 4; ++j)
          acc[i][j] = __builtin_amdgcn_mfma_f32_16x16x32_bf16(a[i], b[j], acc[i][j], 0, 0, 0);
    }
    __syncthreads();
  }

  const int ccol = lane & 15;
  const int crow = (lane >> 4) * 4;
#pragma unroll
  for (int j = 0; j < 4; ++j) {
    const int col = nBase + wn + j * 16 + ccol;
    const float bv = bias[col];
#pragma unroll
    for (int i = 0; i < 4; ++i) {
      const size_t rb = (size_t)(mBase + wm + i * 16 + crow) * OUT_F + col;
#pragma unroll
      for (int t = 0; t < 4; ++t)
        C[rb + (size_t)t * OUT_F] = acc[i][j][t] + bv;
    }
  }
}

extern "C" void kernel_launch(void* const* d_in, const int* in_sizes, int n_in,
                              void* d_out, int out_size, void* d_ws, size_t ws_size,
                              hipStream_t stream) {
  const float* x  = (const float*)d_in[0];
  const int*   wp = (const int*)d_in[1];
  const float* sc = (const float*)d_in[2];
  const float* bi = (const float*)d_in[3];
  float* out = (float*)d_out;

  const size_t bBytes = (size_t)OUT_F * IN_F * 2;   // 33.5 MB bf16 W
  const size_t aBytes = (size_t)M_TOT * IN_F * 2;   // 67 MB bf16 x
  dim3 grid(OUT_F / BN, M_TOT / BM);                // (32, 64)

  if (ws_size >= aBytes + bBytes) {
    u16* B = (u16*)d_ws;
    u16* A = (u16*)((char*)d_ws + bBytes);
    k_dequant_w<<<2048, 256, 0, stream>>>(wp, sc, B);
    k_convert_x<<<4096, 256, 0, stream>>>(x, A);
    k_gemm<<<grid, 256, 0, stream>>>(A, B, bi, out);
  } else {
    k_gemm_fused<<<grid, 256, 0, stream>>>(x, wp, sc, bi, out);
  }
}